// Round 1
// baseline (600.589 us; speedup 1.0000x reference)
//
#include <hip/hip_runtime.h>

// GCN layer: out = relu(x @ W_self^T + b_self + segment_mean(x[src], dst) @ W_neigh^T)
// N = 100000 nodes, D = 64, E = 1.25M edges.

__global__ void gcn_scatter(const float* __restrict__ x,
                            const int* __restrict__ src,
                            const int* __restrict__ dst,
                            float* __restrict__ agg,
                            float* __restrict__ deg,
                            int E) {
  long long gid = (long long)blockIdx.x * blockDim.x + threadIdx.x;
  int e = (int)(gid >> 6);   // one 64-lane wave per edge
  int d = (int)(gid & 63);   // feature dim = lane
  if (e >= E) return;
  int s = src[e];            // wave-uniform -> broadcast load
  int t = dst[e];
  // coalesced 256B row read; device-scope fp32 atomic scatter
  atomicAdd(&agg[(long long)t * 64 + d], x[(long long)s * 64 + d]);
  if (d == 0) atomicAdd(&deg[t], 1.0f);
}

__global__ void gcn_finish(const float* __restrict__ x,
                           const float* __restrict__ agg,
                           const float* __restrict__ deg,
                           const float* __restrict__ Wself,
                           const float* __restrict__ bself,
                           const float* __restrict__ Wneigh,
                           float* __restrict__ out,
                           int N) {
  // Weights stored TRANSPOSED in LDS: sW[k*64 + o] = W[o*64 + k]
  // so lane o reads consecutive addresses (2 lanes/bank = free on CDNA4).
  __shared__ float sWs[64 * 64];
  __shared__ float sWn[64 * 64];
  for (int i = threadIdx.x; i < 64 * 64; i += blockDim.x) {
    int o = i >> 6, k = i & 63;
    sWs[k * 64 + o] = Wself[i];
    sWn[k * 64 + o] = Wneigh[i];
  }
  __syncthreads();

  int o = threadIdx.x & 63;        // output dim = lane
  int waveInBlock = threadIdx.x >> 6;
  int wavesPerBlock = blockDim.x >> 6;
  float b = bself[o];

  for (long long node = (long long)blockIdx.x * wavesPerBlock + waveInBlock;
       node < N;
       node += (long long)gridDim.x * wavesPerBlock) {
    float xv = x[node * 64 + o];    // coalesced row load, one per lane
    float av = agg[node * 64 + o];
    float dg = deg[node];           // wave-uniform
    float inv = 1.0f / (dg < 1.0f ? 1.0f : dg);
    float accS = 0.f, accN = 0.f;
#pragma unroll
    for (int i = 0; i < 64; i++) {
      // broadcast x[node][i] to all lanes via shuffle; W rows from LDS
      accS = fmaf(__shfl(xv, i, 64), sWs[i * 64 + o], accS);
      accN = fmaf(__shfl(av, i, 64), sWn[i * 64 + o], accN);
    }
    float v = accS + b + accN * inv;
    out[node * 64 + o] = v > 0.f ? v : 0.f;
  }
}

extern "C" void kernel_launch(void* const* d_in, const int* in_sizes, int n_in,
                              void* d_out, int out_size, void* d_ws, size_t ws_size,
                              hipStream_t stream) {
  const float* x      = (const float*)d_in[0];
  const int*   eidx   = (const int*)d_in[1];
  const float* Wself  = (const float*)d_in[2];
  const float* bself  = (const float*)d_in[3];
  const float* Wneigh = (const float*)d_in[4];
  float* out = (float*)d_out;

  const int N = in_sizes[0] / 64;
  const int E = in_sizes[1] / 2;
  const int* src = eidx;        // edge_index row 0
  const int* dst = eidx + E;    // edge_index row 1

  float* agg = (float*)d_ws;                       // [N*64]
  float* deg = agg + (long long)N * 64;            // [N]
  size_t zero_bytes = ((size_t)N * 64 + (size_t)N) * sizeof(float);

  // ws is re-poisoned to 0xAA before every timed launch -> must zero each call.
  hipMemsetAsync(d_ws, 0, zero_bytes, stream);

  long long scatter_threads = (long long)E * 64;
  int scatter_blocks = (int)((scatter_threads + 255) / 256);
  gcn_scatter<<<scatter_blocks, 256, 0, stream>>>(x, src, dst, agg, deg, E);

  gcn_finish<<<2048, 256, 0, stream>>>(x, agg, deg, Wself, bself, Wneigh, out, N);
}

// Round 2
// 353.294 us; speedup vs baseline: 1.7000x; 1.7000x over previous
//
#include <hip/hip_runtime.h>

// GCN layer: out = relu(x @ W_self^T + b_self + segment_mean(x[src], dst) @ W_neigh^T)
// N = 100000 nodes, D = 64, E = 1.25M edges.
//
// Pipeline: hist -> scan (3 kernels) -> CSR fill -> per-wave gather (no atomics)
//           -> register-tiled fp32 GEMM epilogue.
// agg is stored in d_out (each GEMM block reads its own tile before overwriting it).

__global__ __launch_bounds__(256) void gcn_hist(const int* __restrict__ dst,
                                                int* __restrict__ deg, int E) {
  int e = blockIdx.x * 256 + threadIdx.x;
  if (e < E) atomicAdd(&deg[dst[e]], 1);
}

__global__ __launch_bounds__(256) void scan_blocksum(const int* __restrict__ deg,
                                                     int* __restrict__ bsum, int N) {
  __shared__ int red[256];
  int base = blockIdx.x * 1024;
  int sum = 0;
  for (int i = threadIdx.x; i < 1024; i += 256) {
    int g = base + i;
    sum += (g < N) ? deg[g] : 0;
  }
  red[threadIdx.x] = sum;
  __syncthreads();
  for (int s = 128; s > 0; s >>= 1) {
    if (threadIdx.x < s) red[threadIdx.x] += red[threadIdx.x + s];
    __syncthreads();
  }
  if (threadIdx.x == 0) bsum[blockIdx.x] = red[0];
}

__global__ __launch_bounds__(128) void scan_tops(const int* __restrict__ bsum,
                                                 int* __restrict__ bsumEx, int nb) {
  __shared__ int sh[128];
  int t = threadIdx.x;
  int v0 = (t < nb) ? bsum[t] : 0;
  sh[t] = v0;
  __syncthreads();
  for (int off = 1; off < 128; off <<= 1) {
    int v = (t >= off) ? sh[t - off] : 0;
    __syncthreads();
    sh[t] += v;
    __syncthreads();
  }
  if (t < nb) bsumEx[t] = sh[t] - v0;  // exclusive scan of block sums
}

__global__ __launch_bounds__(256) void scan_write(const int* __restrict__ deg,
                                                  const int* __restrict__ bsumEx,
                                                  int* __restrict__ rowptr,
                                                  int* __restrict__ cursor,
                                                  int N, int E) {
  int t = threadIdx.x;
  int base = blockIdx.x * 1024 + t * 4;
  int v[4];
#pragma unroll
  for (int i = 0; i < 4; ++i) {
    int g = base + i;
    v[i] = (g < N) ? deg[g] : 0;
  }
  int t0 = v[0], t1 = t0 + v[1], t2 = t1 + v[2], tot = t2 + v[3];
  // wave-level exclusive scan of per-thread totals
  int lane = t & 63;
  int inc = tot;
#pragma unroll
  for (int off = 1; off < 64; off <<= 1) {
    int u = __shfl_up(inc, off, 64);
    if (lane >= off) inc += u;
  }
  int waveEx = inc - tot;
  __shared__ int wsum[4];
  if (lane == 63) wsum[t >> 6] = inc;
  __syncthreads();
  int blockOff = 0;
  for (int w = 0; w < (t >> 6); ++w) blockOff += wsum[w];
  int ex = bsumEx[blockIdx.x] + blockOff + waveEx;
  int p[4] = {ex, ex + t0, ex + t1, ex + t2};
#pragma unroll
  for (int i = 0; i < 4; ++i) {
    int g = base + i;
    if (g < N) { rowptr[g] = p[i]; cursor[g] = p[i]; }
  }
  if (blockIdx.x == 0 && t == 0) rowptr[N] = E;
}

__global__ __launch_bounds__(256) void gcn_fill(const int* __restrict__ src,
                                                const int* __restrict__ dst,
                                                int* __restrict__ cursor,
                                                int* __restrict__ col, int E) {
  int e = blockIdx.x * 256 + threadIdx.x;
  if (e < E) {
    int t = dst[e];
    int p = atomicAdd(&cursor[t], 1);
    col[p] = src[e];
  }
}

// One 64-lane wave per node: lane = feature dim. Coalesced 256B row reads,
// register accumulation, no atomics. Writes mean directly (deg folded in).
__global__ __launch_bounds__(256) void gcn_gather(const float* __restrict__ x,
                                                  const int* __restrict__ rowptr,
                                                  const int* __restrict__ col,
                                                  float* __restrict__ agg, int N) {
  int gid = blockIdx.x * 256 + threadIdx.x;
  int node = gid >> 6, lane = gid & 63;
  if (node >= N) return;
  int s = rowptr[node], e = rowptr[node + 1];
  float a0 = 0.f, a1 = 0.f, a2 = 0.f, a3 = 0.f;
  int j = s;
  for (; j + 4 <= e; j += 4) {  // 4 independent loads in flight per wave
    int c0 = col[j], c1 = col[j + 1], c2 = col[j + 2], c3 = col[j + 3];
    a0 += x[c0 * 64 + lane];
    a1 += x[c1 * 64 + lane];
    a2 += x[c2 * 64 + lane];
    a3 += x[c3 * 64 + lane];
  }
  for (; j < e; ++j) a0 += x[col[j] * 64 + lane];
  float cnt = (float)(e - s);
  float inv = 1.0f / (cnt < 1.f ? 1.f : cnt);
  agg[node * 64 + lane] = (a0 + a1 + a2 + a3) * inv;
}

static __device__ inline void fma4(float4& a, float s, const float4& w) {
  a.x = fmaf(s, w.x, a.x);
  a.y = fmaf(s, w.y, a.y);
  a.z = fmaf(s, w.z, a.z);
  a.w = fmaf(s, w.w, a.w);
}

// 64-node tile per block; thread (tn,to) computes nodes 4tn..4tn+3 x outs 4to..4to+3.
// Per k-step: 4 ds_read_b128 feed 32 FMAs (LDS-pipe ~12K cyc/block, FMA ~4K).
// agg_out is d_out: holds agg (mean) on entry, final output on exit; each block
// only touches its own 64-node tile, and reads it fully before the sync.
__global__ __launch_bounds__(256) void gcn_gemm(const float* __restrict__ x,
                                                float* __restrict__ agg_out,
                                                const float* __restrict__ Wself,
                                                const float* __restrict__ bself,
                                                const float* __restrict__ Wneigh,
                                                int N) {
  __shared__ __align__(16) float sWs[64 * 64];  // sWs[k*64+o] = Wself[o][k]
  __shared__ __align__(16) float sWn[64 * 64];
  __shared__ __align__(16) float xT[64 * 68];   // xT[k*68+n] = x[node][k], padded
  __shared__ __align__(16) float aT[64 * 68];
  int tid = threadIdx.x;
  int gBase = blockIdx.x * 64;

  for (int i = tid; i < 4096; i += 256) {  // stage weights transposed
    int o = i >> 6, k = i & 63;
    sWs[k * 64 + o] = Wself[i];
    sWn[k * 64 + o] = Wneigh[i];
  }
  for (int i = tid; i < 4096; i += 256) {  // stage x/agg tiles transposed
    int n = i >> 6, k = i & 63;            // per-wave: n uniform, k = lane (coalesced)
    int node = gBase + n;
    float xv = 0.f, av = 0.f;
    if (node < N) {
      xv = x[node * 64 + k];
      av = agg_out[node * 64 + k];
    }
    xT[k * 68 + n] = xv;
    aT[k * 68 + n] = av;
  }
  __syncthreads();

  int to = tid & 15, tn = tid >> 4;
  float4 acc[4];
#pragma unroll
  for (int i = 0; i < 4; ++i) acc[i] = make_float4(0.f, 0.f, 0.f, 0.f);

#pragma unroll 8
  for (int k = 0; k < 64; ++k) {
    float4 xa = *(const float4*)&xT[k * 68 + 4 * tn];
    float4 aa = *(const float4*)&aT[k * 68 + 4 * tn];
    float4 ws = *(const float4*)&sWs[k * 64 + 4 * to];
    float4 wn = *(const float4*)&sWn[k * 64 + 4 * to];
    fma4(acc[0], xa.x, ws); fma4(acc[0], aa.x, wn);
    fma4(acc[1], xa.y, ws); fma4(acc[1], aa.y, wn);
    fma4(acc[2], xa.z, ws); fma4(acc[2], aa.z, wn);
    fma4(acc[3], xa.w, ws); fma4(acc[3], aa.w, wn);
  }

  float4 bv = *(const float4*)&bself[4 * to];
#pragma unroll
  for (int i = 0; i < 4; ++i) {
    int node = gBase + 4 * tn + i;
    if (node < N) {
      float4 v = acc[i];
      v.x = fmaxf(v.x + bv.x, 0.f);
      v.y = fmaxf(v.y + bv.y, 0.f);
      v.z = fmaxf(v.z + bv.z, 0.f);
      v.w = fmaxf(v.w + bv.w, 0.f);
      *(float4*)&agg_out[node * 64 + 4 * to] = v;  // coalesced 16B/lane
    }
  }
}

extern "C" void kernel_launch(void* const* d_in, const int* in_sizes, int n_in,
                              void* d_out, int out_size, void* d_ws, size_t ws_size,
                              hipStream_t stream) {
  const float* x      = (const float*)d_in[0];
  const int*   eidx   = (const int*)d_in[1];
  const float* Wself  = (const float*)d_in[2];
  const float* bself  = (const float*)d_in[3];
  const float* Wneigh = (const float*)d_in[4];
  float* out = (float*)d_out;

  const int N = in_sizes[0] / 64;
  const int E = in_sizes[1] / 2;
  const int* src = eidx;      // edge_index row 0
  const int* dst = eidx + E;  // edge_index row 1

  // workspace layout (ints): deg[N] | rowptr[N+1] | cursor[N] | bsum[128] | bsumEx[128] | col[E]
  int* deg    = (int*)d_ws;
  int* rowptr = deg + N;
  int* cursor = rowptr + N + 1;
  int* bsum   = cursor + N;
  int* bsumEx = bsum + 128;
  int* col    = bsumEx + 128;

  hipMemsetAsync(deg, 0, (size_t)N * sizeof(int), stream);

  int eb = (E + 255) / 256;
  int nb = (N + 1023) / 1024;  // 98 <= 128

  gcn_hist<<<eb, 256, 0, stream>>>(dst, deg, E);
  scan_blocksum<<<nb, 256, 0, stream>>>(deg, bsum, N);
  scan_tops<<<1, 128, 0, stream>>>(bsum, bsumEx, nb);
  scan_write<<<nb, 256, 0, stream>>>(deg, bsumEx, rowptr, cursor, N, E);
  gcn_fill<<<eb, 256, 0, stream>>>(src, dst, cursor, col, E);

  gcn_gather<<<(N * 64 + 255) / 256, 256, 0, stream>>>(x, rowptr, col, out, N);
  gcn_gemm<<<(N + 63) / 64, 256, 0, stream>>>(x, out, Wself, bself, Wneigh, N);
}